// Round 1
// baseline (27.080 us; speedup 1.0000x reference)
//
#include <hip/hip_runtime.h>
#include <math.h>

#define NB 16
#define KB 32
#define KA 16

__device__ __forceinline__ float softplus_f(float v) {
    // numerically stable log(1 + exp(v)) == logaddexp(v, 0)
    return fmaxf(v, 0.0f) + log1pf(expf(-fabsf(v)));
}

__global__ __launch_bounds__(256) void BucketAdjustedHinge_kernel(
    const float* __restrict__ x,
    const float* __restrict__ x_mins,
    const float* __restrict__ x_maxs,
    const float* __restrict__ clip_los,
    const float* __restrict__ clip_his,
    const float* __restrict__ base_knots,
    const float* __restrict__ base_raw_w,
    const float* __restrict__ base_bias,
    const float* __restrict__ adj_knots,
    const float* __restrict__ adj_raw_w,
    const float* __restrict__ adj_bias,
    const int*   __restrict__ bucket_idx,
    float*       __restrict__ out,
    int n)
{
    __shared__ float s_xmin[NB], s_inv[NB], s_lo[NB], s_hi[NB], s_bias[NB];
    __shared__ float s_bw[KB];
    __shared__ float s_aw[NB][KA + 1];   // +1 pad: spread stride-16 gather over 16 banks

    const int tid = threadIdx.x;

    if (tid < NB) {
        float mn = x_mins[tid], mx = x_maxs[tid];
        s_xmin[tid] = mn;
        s_inv[tid]  = 1.0f / (mx - mn + 1e-12f);
        float lo = clip_los[tid], hi = clip_his[tid];
        // non-finite clip bound => no clipping; max(x,-inf)/min(x,+inf) are identity
        s_lo[tid] = isfinite(lo) ? lo : -INFINITY;
        s_hi[tid] = isfinite(hi) ? hi :  INFINITY;
        s_bias[tid] = adj_bias[tid] + base_bias[0];
    }
    if (tid < KB) s_bw[tid] = softplus_f(base_raw_w[tid]);
    if (tid < NB * KA) s_aw[tid >> 4][tid & (KA - 1)] = softplus_f(adj_raw_w[tid]);
    __syncthreads();

    // Bucket-independent constants -> registers. Knots come from uniform global
    // addresses (scalar loads -> SGPRs); softplus'd base weights broadcast from LDS.
    float rbk[KB], rbw[KB], rak[KA];
    #pragma unroll
    for (int k = 0; k < KB; ++k) { rbk[k] = base_knots[k]; rbw[k] = s_bw[k]; }
    #pragma unroll
    for (int k = 0; k < KA; ++k) { rak[k] = adj_knots[k]; }

    const int n4 = n >> 2;
    const int stride = gridDim.x * blockDim.x;
    const float4* __restrict__ x4v = (const float4*)x;
    const int4*   __restrict__ b4v = (const int4*)bucket_idx;
    float4*       __restrict__ o4v = (float4*)out;

    for (int i = blockIdx.x * blockDim.x + tid; i < n4; i += stride) {
        const float4 xv = x4v[i];
        const int4   bv = b4v[i];
        const float xs[4] = {xv.x, xv.y, xv.z, xv.w};
        const int   bs[4] = {bv.x, bv.y, bv.z, bv.w};
        float ox[4];
        #pragma unroll
        for (int j = 0; j < 4; ++j) {
            const int b = bs[j];
            float xc  = fminf(fmaxf(xs[j], s_lo[b]), s_hi[b]);
            float x01 = (xc - s_xmin[b]) * s_inv[b];
            x01 = fminf(fmaxf(x01, 0.0f), 1.0f);
            float acc = s_bias[b];
            const float* __restrict__ aw = s_aw[b];
            #pragma unroll
            for (int k = 0; k < KB; ++k)
                acc = fmaf(rbw[k], fminf(x01, rbk[k]), acc);
            #pragma unroll
            for (int k = 0; k < KA; ++k)
                acc = fmaf(aw[k], fminf(x01, rak[k]), acc);
            ox[j] = acc;
        }
        o4v[i] = make_float4(ox[0], ox[1], ox[2], ox[3]);
    }

    // tail (n % 4 != 0) — unused for N=4M but kept correct
    const int rem_start = n4 << 2;
    for (int i = rem_start + blockIdx.x * blockDim.x + tid; i < n; i += stride) {
        const int b = bucket_idx[i];
        float xc  = fminf(fmaxf(x[i], s_lo[b]), s_hi[b]);
        float x01 = (xc - s_xmin[b]) * s_inv[b];
        x01 = fminf(fmaxf(x01, 0.0f), 1.0f);
        float acc = s_bias[b];
        #pragma unroll
        for (int k = 0; k < KB; ++k)
            acc = fmaf(rbw[k], fminf(x01, rbk[k]), acc);
        #pragma unroll
        for (int k = 0; k < KA; ++k)
            acc = fmaf(s_aw[b][k], fminf(x01, rak[k]), acc);
        out[i] = acc;
    }
}

extern "C" void kernel_launch(void* const* d_in, const int* in_sizes, int n_in,
                              void* d_out, int out_size, void* d_ws, size_t ws_size,
                              hipStream_t stream) {
    const float* x          = (const float*)d_in[0];
    const float* x_mins     = (const float*)d_in[1];
    const float* x_maxs     = (const float*)d_in[2];
    const float* clip_los   = (const float*)d_in[3];
    const float* clip_his   = (const float*)d_in[4];
    const float* base_knots = (const float*)d_in[5];
    const float* base_raw_w = (const float*)d_in[6];
    const float* base_bias  = (const float*)d_in[7];
    const float* adj_knots  = (const float*)d_in[8];
    const float* adj_raw_w  = (const float*)d_in[9];
    const float* adj_bias   = (const float*)d_in[10];
    const int*   bucket_idx = (const int*)d_in[11];
    float* out = (float*)d_out;

    const int n = in_sizes[0];
    const int blocks = 2048;   // grid-stride; ~2 float4 iters/thread at N=4M
    BucketAdjustedHinge_kernel<<<blocks, 256, 0, stream>>>(
        x, x_mins, x_maxs, clip_los, clip_his,
        base_knots, base_raw_w, base_bias,
        adj_knots, adj_raw_w, adj_bias,
        bucket_idx, out, n);
}